// Round 7
// baseline (628.518 us; speedup 1.0000x reference)
//
#include <hip/hip_runtime.h>
#include <hip/hip_bf16.h>

#define NEG_SLOPE 0.2f
#define BUK_SHIFT 9
#define BUK_SIZE 512
#define BUK_CAP 16384

typedef unsigned short u16;
typedef __attribute__((ext_vector_type(8))) short s8v;
typedef __attribute__((ext_vector_type(4))) float f4v;

__device__ __forceinline__ int rl_i(int v, int l) { return __builtin_amdgcn_readlane(v, l); }
__device__ __forceinline__ float rl_f(float v, int l) {
    union { float f; int i; } u;
    u.f = v;
    u.i = __builtin_amdgcn_readlane(u.i, l);
    return u.f;
}
__device__ __forceinline__ u16 f2bf(float v) {
    unsigned u = __float_as_uint(v);
    unsigned r = u + 0x7FFFu + ((u >> 16) & 1u);
    return (u16)(r >> 16);
}
__device__ __forceinline__ float bf2f(u16 h) { return __uint_as_float(((unsigned)h) << 16); }

// ---------------- binned CSR build ----------------

__global__ void k_zero(int* g_cnt, int nb) {
    int i = blockIdx.x * blockDim.x + threadIdx.x;
    if (i < nb) g_cnt[i] = 0;
}

__launch_bounds__(256)
__global__ void k_binscatter(const int* __restrict__ ei, int* g_cnt, int* buckets,
                             int E, int nb) {
    __shared__ int lcnt[256], lbase[256], lcur[256];
    int t = threadIdx.x;
    if (t < nb) {
        lcnt[t] = 0;
        lcur[t] = 0;
    }
    __syncthreads();
    int tile0 = blockIdx.x * 4096;
    int pk[16], bk[16];
#pragma unroll
    for (int k = 0; k < 16; k++) {
        int idx = tile0 + k * 256 + t;
        bk[k] = -1;
        if (idx < E) {
            int s = ei[idx];
            int d = ei[E + idx];
            bk[k] = d >> BUK_SHIFT;
            pk[k] = (s << BUK_SHIFT) | (d & (BUK_SIZE - 1));
            atomicAdd(&lcnt[bk[k]], 1);
        }
    }
    __syncthreads();
    if (t < nb && lcnt[t] > 0) lbase[t] = atomicAdd(&g_cnt[t], lcnt[t]);
    __syncthreads();
#pragma unroll
    for (int k = 0; k < 16; k++) {
        if (bk[k] >= 0) {
            int p = lbase[bk[k]] + atomicAdd(&lcur[bk[k]], 1);
            if (p < BUK_CAP) buckets[(bk[k] << 14) + p] = pk[k];
        }
    }
}

__global__ void k_bucket_scan(const int* __restrict__ g_cnt, int* bucket_off, int nb, int n) {
    __shared__ int s[256];
    int t = threadIdx.x;
    int selfc = 0;
    if (t < nb) {
        int lo = t * BUK_SIZE;
        selfc = min(BUK_SIZE, n - lo);
    }
    int v = (t < nb) ? (min(g_cnt[t], BUK_CAP) + selfc) : 0;
    s[t] = v;
    __syncthreads();
    for (int off = 1; off < 256; off <<= 1) {
        int x = (t >= off) ? s[t - off] : 0;
        __syncthreads();
        s[t] += x;
        __syncthreads();
    }
    if (t < nb) bucket_off[t] = s[t] - v;
    if (t == nb - 1) bucket_off[nb] = s[t];
}

__launch_bounds__(512)
__global__ void k_csr(const int* __restrict__ g_cnt, const int* __restrict__ bucket_off,
                      const int* __restrict__ buckets, int* csr_ptr, int* csr_src,
                      int n, int nb) {
    __shared__ int lcnt[512], lsc[512], lcur[512];
    int b = blockIdx.x;
    int t = threadIdx.x;
    int nodes = min(BUK_SIZE, n - b * BUK_SIZE);
    int cnt = min(g_cnt[b], BUK_CAP);
    int boff = bucket_off[b];
    const int* bp = &buckets[b << 14];
    lcnt[t] = 0;
    __syncthreads();
    for (int i = t; i < cnt; i += 512) atomicAdd(&lcnt[bp[i] & (BUK_SIZE - 1)], 1);
    __syncthreads();
    int myc = (t < nodes) ? (lcnt[t] + 1) : 0;
    lsc[t] = myc;
    __syncthreads();
    for (int off = 1; off < 512; off <<= 1) {
        int x = (t >= off) ? lsc[t - off] : 0;
        __syncthreads();
        lsc[t] += x;
        __syncthreads();
    }
    int excl = lsc[t] - myc;
    lcur[t] = excl;
    if (t < nodes) csr_ptr[b * BUK_SIZE + t] = boff + excl;
    if (b == nb - 1 && t == 0) csr_ptr[n] = bucket_off[nb];
    __syncthreads();
    for (int i = t; i < cnt; i += 512) {
        int v = bp[i];
        int ld = v & (BUK_SIZE - 1);
        int p = atomicAdd(&lcur[ld], 1);
        csr_src[boff + p] = v >> BUK_SHIFT;
    }
    if (t < nodes) {
        int p = atomicAdd(&lcur[t], 1);
        csr_src[boff + p] = b * BUK_SIZE + t;
    }
}

// ---------------- fp32 -> bf16 hi/lo split (layer-1 X, and W transpose) ----------------

__global__ void k_split(const float* __restrict__ x, u16* __restrict__ XH,
                        u16* __restrict__ XL, long total) {
    long i = ((long)blockIdx.x * 256 + threadIdx.x) * 4;
    if (i < total) {
        float4 v = *(const float4*)&x[i];
        ushort4 h, l;
        h.x = f2bf(v.x); l.x = f2bf(v.x - bf2f(h.x));
        h.y = f2bf(v.y); l.y = f2bf(v.y - bf2f(h.y));
        h.z = f2bf(v.z); l.z = f2bf(v.z - bf2f(h.z));
        h.w = f2bf(v.w); l.w = f2bf(v.w - bf2f(h.w));
        *(ushort4*)&XH[i] = h;
        *(ushort4*)&XL[i] = l;
    }
}

// W[128,M] -> WTh/WTl[M,128] bf16
__global__ void k_wsplit(const float* __restrict__ W, u16* __restrict__ WTh,
                         u16* __restrict__ WTl, int M) {
    int t = blockIdx.x * 256 + threadIdx.x;
    if (t < 128 * M) {
        int k = t / M, c = t % M;
        float v = W[t];
        u16 h = f2bf(v);
        u16 l = f2bf(v - bf2f(h));
        WTh[c * 128 + k] = h;
        WTl[c * 128 + k] = l;
    }
}

// ---------------- MFMA GEMM (bf16x3 split) + fused attention logits ----------------
// Block: 256 thr = 4 waves; block tile 128 rows x M cols; wave tile 32 rows x M cols.
// 16x16x32 bf16 MFMA. A-frag: lane reads X[R0+rt*16+(lane&15)][ch*32+(lane>>4)*8 ..+8].
// B-frag: lane reads WT[ct*16+(lane&15)][same k-slice]. C: col=lane&15, row=quad*4+reg.

template <int M>
__launch_bounds__(256)
__global__ void k_gemm_mfma(const u16* __restrict__ XH, const u16* __restrict__ XL,
                            const u16* __restrict__ WTh, const u16* __restrict__ WTl,
                            const float* __restrict__ asrc, const float* __restrict__ adst,
                            float* __restrict__ Hout, float* __restrict__ als,
                            float* __restrict__ ald, int nrows) {
    const int CT = M / 16;
    const int H = (M == 128) ? 2 : 1;
    int tid = threadIdx.x;
    int wv = tid >> 6, lane = tid & 63;
    int q = lane >> 4, nl = lane & 15;
    int R0 = blockIdx.x * 128 + wv * 32;

    f4v acc[2][CT];
    f4v z4 = {0.f, 0.f, 0.f, 0.f};
#pragma unroll
    for (int rt = 0; rt < 2; rt++)
#pragma unroll
        for (int ct = 0; ct < CT; ct++) acc[rt][ct] = z4;

#pragma unroll
    for (int ch = 0; ch < 4; ch++) {
        int koff = ch * 32 + q * 8;
        s8v ah0 = *(const s8v*)&XH[(size_t)(R0 + nl) * 128 + koff];
        s8v al0 = *(const s8v*)&XL[(size_t)(R0 + nl) * 128 + koff];
        s8v ah1 = *(const s8v*)&XH[(size_t)(R0 + 16 + nl) * 128 + koff];
        s8v al1 = *(const s8v*)&XL[(size_t)(R0 + 16 + nl) * 128 + koff];
#pragma unroll
        for (int ct = 0; ct < CT; ct++) {
            s8v bh = *(const s8v*)&WTh[(ct * 16 + nl) * 128 + koff];
            s8v bl = *(const s8v*)&WTl[(ct * 16 + nl) * 128 + koff];
            acc[0][ct] = __builtin_amdgcn_mfma_f32_16x16x32_bf16(ah0, bh, acc[0][ct], 0, 0, 0);
            acc[0][ct] = __builtin_amdgcn_mfma_f32_16x16x32_bf16(ah0, bl, acc[0][ct], 0, 0, 0);
            acc[0][ct] = __builtin_amdgcn_mfma_f32_16x16x32_bf16(al0, bh, acc[0][ct], 0, 0, 0);
            acc[1][ct] = __builtin_amdgcn_mfma_f32_16x16x32_bf16(ah1, bh, acc[1][ct], 0, 0, 0);
            acc[1][ct] = __builtin_amdgcn_mfma_f32_16x16x32_bf16(ah1, bl, acc[1][ct], 0, 0, 0);
            acc[1][ct] = __builtin_amdgcn_mfma_f32_16x16x32_bf16(al1, bh, acc[1][ct], 0, 0, 0);
        }
    }

    // attention-logit partials (per lane: fixed col = ct*16+nl, rows q*4+reg)
    float av[CT], dvv[CT];
#pragma unroll
    for (int ct = 0; ct < CT; ct++) {
        av[ct] = asrc[ct * 16 + nl];
        dvv[ct] = adst[ct * 16 + nl];
    }
    float ps[2][4][2], pd[2][4][2];
#pragma unroll
    for (int rt = 0; rt < 2; rt++)
#pragma unroll
        for (int r = 0; r < 4; r++)
            for (int h = 0; h < 2; h++) ps[rt][r][h] = pd[rt][r][h] = 0.f;
#pragma unroll
    for (int rt = 0; rt < 2; rt++)
#pragma unroll
        for (int ct = 0; ct < CT; ct++) {
            int h = (M == 128) ? (ct >> 2) : 0;
#pragma unroll
            for (int r = 0; r < 4; r++) {
                ps[rt][r][h] = fmaf(acc[rt][ct][r], av[ct], ps[rt][r][h]);
                pd[rt][r][h] = fmaf(acc[rt][ct][r], dvv[ct], pd[rt][r][h]);
            }
        }

    // store H tile
#pragma unroll
    for (int rt = 0; rt < 2; rt++)
#pragma unroll
        for (int ct = 0; ct < CT; ct++)
#pragma unroll
            for (int r = 0; r < 4; r++) {
                int row = R0 + rt * 16 + q * 4 + r;
                if (row < nrows) Hout[(size_t)row * M + ct * 16 + nl] = acc[rt][ct][r];
            }

    // reduce logits across the 16 cols (n-lanes) and store
#pragma unroll
    for (int rt = 0; rt < 2; rt++)
#pragma unroll
        for (int r = 0; r < 4; r++)
#pragma unroll
            for (int h = 0; h < H; h++) {
                float v1 = ps[rt][r][h], v2 = pd[rt][r][h];
                for (int m = 1; m <= 8; m <<= 1) {
                    v1 += __shfl_xor(v1, m);
                    v2 += __shfl_xor(v2, m);
                }
                int row = R0 + rt * 16 + q * 4 + r;
                if (nl == 0 && row < nrows) {
                    als[(size_t)row * H + h] = v1;
                    ald[(size_t)row * H + h] = v2;
                }
            }
}

// ---------------- aggregation M=128 (r4 winner: readlane, 2 loads in flight) ----------------
// Writes bf16 hi/lo (next layer's GEMM input), with ReLU.

__global__ void k_agg128(const int* __restrict__ ptr, const int* __restrict__ srcv,
                         const float* __restrict__ Hf, const float* __restrict__ als,
                         const float* __restrict__ ald, const float* __restrict__ bias,
                         u16* __restrict__ OutH, u16* __restrict__ OutL, int n) {
    int wid = (blockIdx.x * blockDim.x + threadIdx.x) >> 6;
    int lane = threadIdx.x & 63;
    if (wid >= n) return;
    int start = ptr[wid], end = ptr[wid + 1];
    float2 adv = *(const float2*)&ald[(size_t)wid * 2];
    int hi = lane >> 5;
    int myq = (lane >> 4) & 1;
    int colbase = (lane & 31) * 4;
    float z0 = 0.f, z1 = 0.f;
    float4 acc = make_float4(0.f, 0.f, 0.f, 0.f);
    float4 acc2 = make_float4(0.f, 0.f, 0.f, 0.f);

    for (int base = start; base < end; base += 64) {
        int i = base + lane;
        int s_l = 0;
        float ex0 = 0.f, ex1 = 0.f;
        if (i < end) {
            s_l = srcv[i];
            float2 av = *(const float2*)&als[(size_t)s_l * 2];
            float e0 = av.x + adv.x;
            e0 = e0 > 0.f ? e0 : NEG_SLOPE * e0;
            ex0 = __expf(e0);
            float e1 = av.y + adv.y;
            e1 = e1 > 0.f ? e1 : NEG_SLOPE * e1;
            ex1 = __expf(e1);
        }
        z0 += ex0;
        z1 += ex1;
        int cntj = min(64, end - base);
        int jp = 0;
        for (; jp + 4 <= cntj; jp += 4) {
            int sA = rl_i(s_l, jp), sB = rl_i(s_l, jp + 1);
            int sC = rl_i(s_l, jp + 2), sD = rl_i(s_l, jp + 3);
            float a0 = rl_f(ex0, jp), a1 = rl_f(ex1, jp);
            float b0 = rl_f(ex0, jp + 1), b1 = rl_f(ex1, jp + 1);
            float c0 = rl_f(ex0, jp + 2), c1 = rl_f(ex1, jp + 2);
            float d0 = rl_f(ex0, jp + 3), d1 = rl_f(ex1, jp + 3);
            int r1 = hi ? sB : sA;
            int r2 = hi ? sD : sC;
            float w1 = hi ? (myq ? b1 : b0) : (myq ? a1 : a0);
            float w2 = hi ? (myq ? d1 : d0) : (myq ? c1 : c0);
            float4 h1 = *(const float4*)&Hf[(size_t)r1 * 128 + colbase];
            float4 h2 = *(const float4*)&Hf[(size_t)r2 * 128 + colbase];
            acc.x = fmaf(w1, h1.x, acc.x);
            acc.y = fmaf(w1, h1.y, acc.y);
            acc.z = fmaf(w1, h1.z, acc.z);
            acc.w = fmaf(w1, h1.w, acc.w);
            acc2.x = fmaf(w2, h2.x, acc2.x);
            acc2.y = fmaf(w2, h2.y, acc2.y);
            acc2.z = fmaf(w2, h2.z, acc2.z);
            acc2.w = fmaf(w2, h2.w, acc2.w);
        }
        for (; jp < cntj; jp += 2) {
            int sA = rl_i(s_l, jp);
            float a0 = rl_f(ex0, jp), a1 = rl_f(ex1, jp);
            int sB = sA;
            float b0 = 0.f, b1 = 0.f;
            if (jp + 1 < cntj) {
                sB = rl_i(s_l, jp + 1);
                b0 = rl_f(ex0, jp + 1);
                b1 = rl_f(ex1, jp + 1);
            }
            int r1 = hi ? sB : sA;
            float w1 = hi ? (myq ? b1 : b0) : (myq ? a1 : a0);
            float4 h1 = *(const float4*)&Hf[(size_t)r1 * 128 + colbase];
            acc.x = fmaf(w1, h1.x, acc.x);
            acc.y = fmaf(w1, h1.y, acc.y);
            acc.z = fmaf(w1, h1.z, acc.z);
            acc.w = fmaf(w1, h1.w, acc.w);
        }
    }
    acc.x += acc2.x;
    acc.y += acc2.y;
    acc.z += acc2.z;
    acc.w += acc2.w;
    acc.x += __shfl_xor(acc.x, 32);
    acc.y += __shfl_xor(acc.y, 32);
    acc.z += __shfl_xor(acc.z, 32);
    acc.w += __shfl_xor(acc.w, 32);
    for (int m = 32; m >= 1; m >>= 1) {
        z0 += __shfl_xor(z0, m);
        z1 += __shfl_xor(z1, m);
    }
    if (lane < 32) {
        float zinv = myq ? (1.f / z1) : (1.f / z0);
        float4 b = *(const float4*)&bias[colbase];
        float4 o;
        o.x = fmaxf(fmaf(acc.x, zinv, b.x), 0.f);
        o.y = fmaxf(fmaf(acc.y, zinv, b.y), 0.f);
        o.z = fmaxf(fmaf(acc.z, zinv, b.z), 0.f);
        o.w = fmaxf(fmaf(acc.w, zinv, b.w), 0.f);
        ushort4 hh, ll;
        hh.x = f2bf(o.x); ll.x = f2bf(o.x - bf2f(hh.x));
        hh.y = f2bf(o.y); ll.y = f2bf(o.y - bf2f(hh.y));
        hh.z = f2bf(o.z); ll.z = f2bf(o.z - bf2f(hh.z));
        hh.w = f2bf(o.w); ll.w = f2bf(o.w - bf2f(hh.w));
        *(ushort4*)&OutH[(size_t)wid * 128 + colbase] = hh;
        *(ushort4*)&OutL[(size_t)wid * 128 + colbase] = ll;
    }
}

// ---------------- aggregation M=64 (final layer, fp32 out) ----------------

__launch_bounds__(256)
__global__ void k_agg64(const int* __restrict__ ptr, const int* __restrict__ srcv,
                        const float* __restrict__ Hf, const float* __restrict__ als,
                        const float* __restrict__ ald, const float* __restrict__ bias,
                        float* __restrict__ Out, int n) {
    int wid = blockIdx.x * 4 + (threadIdx.x >> 6);
    int lane = threadIdx.x & 63;
    if (wid >= n) return;
    int start = ptr[wid], end = ptr[wid + 1];
    float ad0 = ald[wid];
    int q = lane >> 4;
    int col = (lane & 15) * 4;
    float z = 0.f;
    float4 a1 = make_float4(0.f, 0.f, 0.f, 0.f);
    float4 a2 = make_float4(0.f, 0.f, 0.f, 0.f);
    float4 a3 = make_float4(0.f, 0.f, 0.f, 0.f);
    float4 a4 = make_float4(0.f, 0.f, 0.f, 0.f);

    for (int base = start; base < end; base += 64) {
        int i = base + lane;
        int s_l = 0;
        float ex0 = 0.f;
        if (i < end) {
            s_l = srcv[i];
            float e = als[s_l] + ad0;
            e = e > 0.f ? e : NEG_SLOPE * e;
            ex0 = __expf(e);
        }
        z += ex0;
        int cntj = min(64, end - base);
        int cnt4 = (cntj + 3) & ~3;
        int jp = 0;
        for (; jp + 16 <= cnt4; jp += 16) {
            int r1 = __shfl(s_l, jp + q);
            float w1 = __shfl(ex0, jp + q);
            int r2 = __shfl(s_l, jp + 4 + q);
            float w2 = __shfl(ex0, jp + 4 + q);
            int r3 = __shfl(s_l, jp + 8 + q);
            float w3 = __shfl(ex0, jp + 8 + q);
            int r4 = __shfl(s_l, jp + 12 + q);
            float w4 = __shfl(ex0, jp + 12 + q);
            float4 h1 = *(const float4*)&Hf[(size_t)r1 * 64 + col];
            float4 h2 = *(const float4*)&Hf[(size_t)r2 * 64 + col];
            float4 h3 = *(const float4*)&Hf[(size_t)r3 * 64 + col];
            float4 h4 = *(const float4*)&Hf[(size_t)r4 * 64 + col];
            a1.x = fmaf(w1, h1.x, a1.x);
            a1.y = fmaf(w1, h1.y, a1.y);
            a1.z = fmaf(w1, h1.z, a1.z);
            a1.w = fmaf(w1, h1.w, a1.w);
            a2.x = fmaf(w2, h2.x, a2.x);
            a2.y = fmaf(w2, h2.y, a2.y);
            a2.z = fmaf(w2, h2.z, a2.z);
            a2.w = fmaf(w2, h2.w, a2.w);
            a3.x = fmaf(w3, h3.x, a3.x);
            a3.y = fmaf(w3, h3.y, a3.y);
            a3.z = fmaf(w3, h3.z, a3.z);
            a3.w = fmaf(w3, h3.w, a3.w);
            a4.x = fmaf(w4, h4.x, a4.x);
            a4.y = fmaf(w4, h4.y, a4.y);
            a4.z = fmaf(w4, h4.z, a4.z);
            a4.w = fmaf(w4, h4.w, a4.w);
        }
        for (; jp < cnt4; jp += 4) {
            int r1 = __shfl(s_l, jp + q);
            float w1 = __shfl(ex0, jp + q);
            float4 h1 = *(const float4*)&Hf[(size_t)r1 * 64 + col];
            a1.x = fmaf(w1, h1.x, a1.x);
            a1.y = fmaf(w1, h1.y, a1.y);
            a1.z = fmaf(w1, h1.z, a1.z);
            a1.w = fmaf(w1, h1.w, a1.w);
        }
    }
    a1.x += a2.x + a3.x + a4.x;
    a1.y += a2.y + a3.y + a4.y;
    a1.z += a2.z + a3.z + a4.z;
    a1.w += a2.w + a3.w + a4.w;
    a1.x += __shfl_xor(a1.x, 16);
    a1.y += __shfl_xor(a1.y, 16);
    a1.z += __shfl_xor(a1.z, 16);
    a1.w += __shfl_xor(a1.w, 16);
    a1.x += __shfl_xor(a1.x, 32);
    a1.y += __shfl_xor(a1.y, 32);
    a1.z += __shfl_xor(a1.z, 32);
    a1.w += __shfl_xor(a1.w, 32);
    for (int m = 32; m >= 1; m >>= 1) z += __shfl_xor(z, m);
    if (lane < 16) {
        float zinv = 1.f / z;
        float4 b = *(const float4*)&bias[col];
        float4 o;
        o.x = fmaf(a1.x, zinv, b.x);
        o.y = fmaf(a1.y, zinv, b.y);
        o.z = fmaf(a1.z, zinv, b.z);
        o.w = fmaf(a1.w, zinv, b.w);
        *(float4*)&Out[(size_t)wid * 64 + col] = o;
    }
}

// ---------------- launch ----------------

extern "C" void kernel_launch(void* const* d_in, const int* in_sizes, int n_in,
                              void* d_out, int out_size, void* d_ws, size_t ws_size,
                              hipStream_t stream) {
    const float* x = (const float*)d_in[0];
    const int* ei = (const int*)d_in[1];
    const float* W1 = (const float*)d_in[2];
    const float* as1 = (const float*)d_in[3];
    const float* ad1 = (const float*)d_in[4];
    const float* b1 = (const float*)d_in[5];
    const float* W2 = (const float*)d_in[6];
    const float* as2 = (const float*)d_in[7];
    const float* ad2 = (const float*)d_in[8];
    const float* b2 = (const float*)d_in[9];
    const float* W3 = (const float*)d_in[10];
    const float* as3 = (const float*)d_in[11];
    const float* ad3 = (const float*)d_in[12];
    const float* b3 = (const float*)d_in[13];

    const int N = in_sizes[0] / 128;
    const int E = in_sizes[1] / 2;
    const int NB = (N + BUK_SIZE - 1) / BUK_SIZE;
    const int Npad = (N + 127) & ~127;

    char* p = (char*)d_ws;
    auto alloc = [&](size_t bytes) -> char* {
        char* r = p;
        p += (bytes + 255) & ~(size_t)255;
        return r;
    };
    int* g_cnt = (int*)alloc(256 * 4);
    int* bucket_off = (int*)alloc(257 * 4);
    int* buckets = (int*)alloc((size_t)NB * BUK_CAP * 4);
    int* csr_ptr = (int*)alloc((size_t)(N + 1) * 4);
    int* csr_src = (int*)alloc((size_t)(E + N) * 4);
    float* als = (float*)alloc((size_t)N * 2 * 4);
    float* aldv = (float*)alloc((size_t)N * 2 * 4);
    float* Hbuf = (float*)alloc((size_t)N * 128 * 4);
    u16* XH = (u16*)alloc((size_t)Npad * 128 * 2);
    u16* XL = (u16*)alloc((size_t)Npad * 128 * 2);
    u16* WTh = (u16*)alloc(128 * 128 * 2);
    u16* WTl = (u16*)alloc(128 * 128 * 2);

    const int nbG = (N + 127) / 128;
    const int nbWave = (N * 64 + 255) / 256;
    const int nbAgg64 = (N + 3) / 4;
    const int nbTile = (E + 4095) / 4096;
    const long totX = (long)N * 128;
    const int nbSplit = (int)((totX / 4 + 255) / 256);

    // ---- binned CSR build (shared by all 3 layers) ----
    k_zero<<<1, 256, 0, stream>>>(g_cnt, 256);
    k_binscatter<<<nbTile, 256, 0, stream>>>(ei, g_cnt, buckets, E, NB);
    k_bucket_scan<<<1, 256, 0, stream>>>(g_cnt, bucket_off, NB, N);
    k_csr<<<NB, 512, 0, stream>>>(g_cnt, bucket_off, buckets, csr_ptr, csr_src, N, NB);

    // ---- layer 1 ----
    k_split<<<nbSplit, 256, 0, stream>>>(x, XH, XL, totX);
    k_wsplit<<<(128 * 128 + 255) / 256, 256, 0, stream>>>(W1, WTh, WTl, 128);
    k_gemm_mfma<128><<<nbG, 256, 0, stream>>>(XH, XL, WTh, WTl, as1, ad1, Hbuf, als, aldv, N);
    k_agg128<<<nbWave, 256, 0, stream>>>(csr_ptr, csr_src, Hbuf, als, aldv, b1, XH, XL, N);

    // ---- layer 2 ----
    k_wsplit<<<(128 * 128 + 255) / 256, 256, 0, stream>>>(W2, WTh, WTl, 128);
    k_gemm_mfma<128><<<nbG, 256, 0, stream>>>(XH, XL, WTh, WTl, as2, ad2, Hbuf, als, aldv, N);
    k_agg128<<<nbWave, 256, 0, stream>>>(csr_ptr, csr_src, Hbuf, als, aldv, b2, XH, XL, N);

    // ---- layer 3 (M=64, mean==identity, no relu) ----
    k_wsplit<<<(128 * 64 + 255) / 256, 256, 0, stream>>>(W3, WTh, WTl, 64);
    k_gemm_mfma<64><<<nbG, 256, 0, stream>>>(XH, XL, WTh, WTl, as3, ad3, Hbuf, als, aldv, N);
    k_agg64<<<nbAgg64, 256, 0, stream>>>(csr_ptr, csr_src, Hbuf, als, aldv, b3,
                                         (float*)d_out, N);
}

// Round 8
// 592.903 us; speedup vs baseline: 1.0601x; 1.0601x over previous
//
#include <hip/hip_runtime.h>
#include <hip/hip_bf16.h>

#define NEG_SLOPE 0.2f
#define BUK_SHIFT 9
#define BUK_SIZE 512
#define BUK_CAP 16384

typedef unsigned short u16;
typedef __attribute__((ext_vector_type(8))) short s8v;
typedef __attribute__((ext_vector_type(4))) float f4v;

__device__ __forceinline__ int rl_i(int v, int l) { return __builtin_amdgcn_readlane(v, l); }
__device__ __forceinline__ float rl_f(float v, int l) {
    union { float f; int i; } u;
    u.f = v;
    u.i = __builtin_amdgcn_readlane(u.i, l);
    return u.f;
}
__device__ __forceinline__ u16 f2bf(float v) {
    unsigned u = __float_as_uint(v);
    unsigned r = u + 0x7FFFu + ((u >> 16) & 1u);
    return (u16)(r >> 16);
}
__device__ __forceinline__ float bf2f(u16 h) { return __uint_as_float(((unsigned)h) << 16); }

// ---------------- binned CSR build ----------------

__global__ void k_zero(int* g_cnt, int nb) {
    int i = blockIdx.x * blockDim.x + threadIdx.x;
    if (i < nb) g_cnt[i] = 0;
}

__launch_bounds__(256)
__global__ void k_binscatter(const int* __restrict__ ei, int* g_cnt, int* buckets,
                             int E, int nb) {
    __shared__ int lcnt[256], lbase[256], lcur[256];
    int t = threadIdx.x;
    if (t < nb) {
        lcnt[t] = 0;
        lcur[t] = 0;
    }
    __syncthreads();
    int tile0 = blockIdx.x * 4096;
    int pk[16], bk[16];
#pragma unroll
    for (int k = 0; k < 16; k++) {
        int idx = tile0 + k * 256 + t;
        bk[k] = -1;
        if (idx < E) {
            int s = ei[idx];
            int d = ei[E + idx];
            bk[k] = d >> BUK_SHIFT;
            pk[k] = (s << BUK_SHIFT) | (d & (BUK_SIZE - 1));
            atomicAdd(&lcnt[bk[k]], 1);
        }
    }
    __syncthreads();
    if (t < nb && lcnt[t] > 0) lbase[t] = atomicAdd(&g_cnt[t], lcnt[t]);
    __syncthreads();
#pragma unroll
    for (int k = 0; k < 16; k++) {
        if (bk[k] >= 0) {
            int p = lbase[bk[k]] + atomicAdd(&lcur[bk[k]], 1);
            if (p < BUK_CAP) buckets[(bk[k] << 14) + p] = pk[k];
        }
    }
}

__global__ void k_bucket_scan(const int* __restrict__ g_cnt, int* bucket_off, int nb, int n) {
    __shared__ int s[256];
    int t = threadIdx.x;
    int selfc = 0;
    if (t < nb) {
        int lo = t * BUK_SIZE;
        selfc = min(BUK_SIZE, n - lo);
    }
    int v = (t < nb) ? (min(g_cnt[t], BUK_CAP) + selfc) : 0;
    s[t] = v;
    __syncthreads();
    for (int off = 1; off < 256; off <<= 1) {
        int x = (t >= off) ? s[t - off] : 0;
        __syncthreads();
        s[t] += x;
        __syncthreads();
    }
    if (t < nb) bucket_off[t] = s[t] - v;
    if (t == nb - 1) bucket_off[nb] = s[t];
}

__launch_bounds__(512)
__global__ void k_csr(const int* __restrict__ g_cnt, const int* __restrict__ bucket_off,
                      const int* __restrict__ buckets, int* csr_ptr, int* csr_src,
                      int n, int nb) {
    __shared__ int lcnt[512], lsc[512], lcur[512];
    int b = blockIdx.x;
    int t = threadIdx.x;
    int nodes = min(BUK_SIZE, n - b * BUK_SIZE);
    int cnt = min(g_cnt[b], BUK_CAP);
    int boff = bucket_off[b];
    const int* bp = &buckets[b << 14];
    lcnt[t] = 0;
    __syncthreads();
    for (int i = t; i < cnt; i += 512) atomicAdd(&lcnt[bp[i] & (BUK_SIZE - 1)], 1);
    __syncthreads();
    int myc = (t < nodes) ? (lcnt[t] + 1) : 0;
    lsc[t] = myc;
    __syncthreads();
    for (int off = 1; off < 512; off <<= 1) {
        int x = (t >= off) ? lsc[t - off] : 0;
        __syncthreads();
        lsc[t] += x;
        __syncthreads();
    }
    int excl = lsc[t] - myc;
    lcur[t] = excl;
    if (t < nodes) csr_ptr[b * BUK_SIZE + t] = boff + excl;
    if (b == nb - 1 && t == 0) csr_ptr[n] = bucket_off[nb];
    __syncthreads();
    for (int i = t; i < cnt; i += 512) {
        int v = bp[i];
        int ld = v & (BUK_SIZE - 1);
        int p = atomicAdd(&lcur[ld], 1);
        csr_src[boff + p] = v >> BUK_SHIFT;
    }
    if (t < nodes) {
        int p = atomicAdd(&lcur[t], 1);
        csr_src[boff + p] = b * BUK_SIZE + t;
    }
}

// ---------------- fp32 -> bf16 hi/lo split, MFMA fragment-tile layout ----------------
// Tile = 16 rows x 32 k = 1KB; u16 index = (rowtile*4 + ch)*512 + ((row&15)+16*q)*8 + j
// where ch=k>>5, q=(k>>3)&3, j=k&7. A wave's s8v frag load is then lane*8 contiguous.

__global__ void k_split(const float* __restrict__ x, u16* __restrict__ XH,
                        u16* __restrict__ XL, int N, int Npad) {
    int t = blockIdx.x * 256 + threadIdx.x;  // one thread per (row, 8-k group)
    int row = t >> 4;
    if (row >= Npad) return;
    int k0 = (t & 15) * 8;
    float v[8];
    if (row < N) {
        float4 a = *(const float4*)&x[(size_t)row * 128 + k0];
        float4 b = *(const float4*)&x[(size_t)row * 128 + k0 + 4];
        v[0] = a.x; v[1] = a.y; v[2] = a.z; v[3] = a.w;
        v[4] = b.x; v[5] = b.y; v[6] = b.z; v[7] = b.w;
    } else {
#pragma unroll
        for (int i = 0; i < 8; i++) v[i] = 0.f;
    }
    u16 h[8], l[8];
#pragma unroll
    for (int i = 0; i < 8; i++) {
        h[i] = f2bf(v[i]);
        l[i] = f2bf(v[i] - bf2f(h[i]));
    }
    int ch = k0 >> 5, q = (k0 >> 3) & 3;
    size_t base = ((size_t)(row >> 4) * 4 + ch) * 512 + ((row & 15) + 16 * q) * 8;
    *(ushort4*)&XH[base] = make_ushort4(h[0], h[1], h[2], h[3]);
    *(ushort4*)&XH[base + 4] = make_ushort4(h[4], h[5], h[6], h[7]);
    *(ushort4*)&XL[base] = make_ushort4(l[0], l[1], l[2], l[3]);
    *(ushort4*)&XL[base + 4] = make_ushort4(l[4], l[5], l[6], l[7]);
}

// W[128,M] -> fragment tiles: tile (ct, ch), col plays "row" role.
__global__ void k_wsplit(const float* __restrict__ W, u16* __restrict__ WTh,
                         u16* __restrict__ WTl, int M) {
    int t = blockIdx.x * 256 + threadIdx.x;
    if (t >= 128 * M) return;
    int c = t >> 7, k = t & 127;
    float v = W[(size_t)k * M + c];
    u16 h = f2bf(v);
    u16 l = f2bf(v - bf2f(h));
    int ct = c >> 4, ch = k >> 5, q = (k >> 3) & 3, j = k & 7;
    size_t addr = ((size_t)ct * 4 + ch) * 512 + ((c & 15) + 16 * q) * 8 + j;
    WTh[addr] = h;
    WTl[addr] = l;
}

// ---------------- MFMA GEMM (bf16x3 split) + fused attention logits ----------------
// 256 thr = 4 waves; block 128 rows x M cols; wave 32 rows (2 row-tiles) x M cols.
// All fragment loads are fully-coalesced 1KB dwordx4 from tile layout.

template <int M>
__launch_bounds__(256)
__global__ void k_gemm_mfma(const u16* __restrict__ XH, const u16* __restrict__ XL,
                            const u16* __restrict__ WTh, const u16* __restrict__ WTl,
                            const float* __restrict__ asrc, const float* __restrict__ adst,
                            float* __restrict__ Hout, float* __restrict__ als,
                            float* __restrict__ ald, int nrows) {
    const int CT = M / 16;
    const int H = (M == 128) ? 2 : 1;
    int tid = threadIdx.x;
    int wv = tid >> 6, lane = tid & 63;
    int q = lane >> 4, nl = lane & 15;
    int R0 = blockIdx.x * 128 + wv * 32;
    int rt0 = R0 >> 4;  // row-tile index

    f4v acc[2][CT];
    f4v z4 = {0.f, 0.f, 0.f, 0.f};
#pragma unroll
    for (int rt = 0; rt < 2; rt++)
#pragma unroll
        for (int ct = 0; ct < CT; ct++) acc[rt][ct] = z4;

#pragma unroll
    for (int ch = 0; ch < 4; ch++) {
        size_t a0 = ((size_t)rt0 * 4 + ch) * 512 + lane * 8;
        size_t a1 = ((size_t)(rt0 + 1) * 4 + ch) * 512 + lane * 8;
        s8v ah0 = *(const s8v*)&XH[a0];
        s8v al0 = *(const s8v*)&XL[a0];
        s8v ah1 = *(const s8v*)&XH[a1];
        s8v al1 = *(const s8v*)&XL[a1];
#pragma unroll
        for (int ct = 0; ct < CT; ct++) {
            size_t bb = ((size_t)ct * 4 + ch) * 512 + lane * 8;
            s8v bh = *(const s8v*)&WTh[bb];
            s8v bl = *(const s8v*)&WTl[bb];
            acc[0][ct] = __builtin_amdgcn_mfma_f32_16x16x32_bf16(ah0, bh, acc[0][ct], 0, 0, 0);
            acc[0][ct] = __builtin_amdgcn_mfma_f32_16x16x32_bf16(ah0, bl, acc[0][ct], 0, 0, 0);
            acc[0][ct] = __builtin_amdgcn_mfma_f32_16x16x32_bf16(al0, bh, acc[0][ct], 0, 0, 0);
            acc[1][ct] = __builtin_amdgcn_mfma_f32_16x16x32_bf16(ah1, bh, acc[1][ct], 0, 0, 0);
            acc[1][ct] = __builtin_amdgcn_mfma_f32_16x16x32_bf16(ah1, bl, acc[1][ct], 0, 0, 0);
            acc[1][ct] = __builtin_amdgcn_mfma_f32_16x16x32_bf16(al1, bh, acc[1][ct], 0, 0, 0);
        }
    }

    float av[CT], dvv[CT];
#pragma unroll
    for (int ct = 0; ct < CT; ct++) {
        av[ct] = asrc[ct * 16 + nl];
        dvv[ct] = adst[ct * 16 + nl];
    }
    float ps[2][4][2], pd[2][4][2];
#pragma unroll
    for (int rt = 0; rt < 2; rt++)
#pragma unroll
        for (int r = 0; r < 4; r++)
            for (int h = 0; h < 2; h++) ps[rt][r][h] = pd[rt][r][h] = 0.f;
#pragma unroll
    for (int rt = 0; rt < 2; rt++)
#pragma unroll
        for (int ct = 0; ct < CT; ct++) {
            int h = (M == 128) ? (ct >> 2) : 0;
#pragma unroll
            for (int r = 0; r < 4; r++) {
                ps[rt][r][h] = fmaf(acc[rt][ct][r], av[ct], ps[rt][r][h]);
                pd[rt][r][h] = fmaf(acc[rt][ct][r], dvv[ct], pd[rt][r][h]);
            }
        }

#pragma unroll
    for (int rt = 0; rt < 2; rt++)
#pragma unroll
        for (int ct = 0; ct < CT; ct++)
#pragma unroll
            for (int r = 0; r < 4; r++) {
                int row = R0 + rt * 16 + q * 4 + r;
                if (row < nrows) Hout[(size_t)row * M + ct * 16 + nl] = acc[rt][ct][r];
            }

#pragma unroll
    for (int rt = 0; rt < 2; rt++)
#pragma unroll
        for (int r = 0; r < 4; r++)
#pragma unroll
            for (int h = 0; h < H; h++) {
                float v1 = ps[rt][r][h], v2 = pd[rt][r][h];
                for (int m = 1; m <= 8; m <<= 1) {
                    v1 += __shfl_xor(v1, m);
                    v2 += __shfl_xor(v2, m);
                }
                int row = R0 + rt * 16 + q * 4 + r;
                if (nl == 0 && row < nrows) {
                    als[(size_t)row * H + h] = v1;
                    ald[(size_t)row * H + h] = v2;
                }
            }
}

// ---------------- aggregation M=128 (readlane, 2 loads in flight) ----------------
// Writes bf16 hi/lo in fragment-tile layout (next layer's GEMM input), with ReLU.

__global__ void k_agg128(const int* __restrict__ ptr, const int* __restrict__ srcv,
                         const float* __restrict__ Hf, const float* __restrict__ als,
                         const float* __restrict__ ald, const float* __restrict__ bias,
                         u16* __restrict__ OutH, u16* __restrict__ OutL, int n) {
    int wid = (blockIdx.x * blockDim.x + threadIdx.x) >> 6;
    int lane = threadIdx.x & 63;
    if (wid >= n) return;
    int start = ptr[wid], end = ptr[wid + 1];
    float2 adv = *(const float2*)&ald[(size_t)wid * 2];
    int hi = lane >> 5;
    int myq = (lane >> 4) & 1;
    int colbase = (lane & 31) * 4;
    float z0 = 0.f, z1 = 0.f;
    float4 acc = make_float4(0.f, 0.f, 0.f, 0.f);
    float4 acc2 = make_float4(0.f, 0.f, 0.f, 0.f);

    for (int base = start; base < end; base += 64) {
        int i = base + lane;
        int s_l = 0;
        float ex0 = 0.f, ex1 = 0.f;
        if (i < end) {
            s_l = srcv[i];
            float2 av = *(const float2*)&als[(size_t)s_l * 2];
            float e0 = av.x + adv.x;
            e0 = e0 > 0.f ? e0 : NEG_SLOPE * e0;
            ex0 = __expf(e0);
            float e1 = av.y + adv.y;
            e1 = e1 > 0.f ? e1 : NEG_SLOPE * e1;
            ex1 = __expf(e1);
        }
        z0 += ex0;
        z1 += ex1;
        int cntj = min(64, end - base);
        int jp = 0;
        for (; jp + 4 <= cntj; jp += 4) {
            int sA = rl_i(s_l, jp), sB = rl_i(s_l, jp + 1);
            int sC = rl_i(s_l, jp + 2), sD = rl_i(s_l, jp + 3);
            float a0 = rl_f(ex0, jp), a1 = rl_f(ex1, jp);
            float b0 = rl_f(ex0, jp + 1), b1 = rl_f(ex1, jp + 1);
            float c0 = rl_f(ex0, jp + 2), c1 = rl_f(ex1, jp + 2);
            float d0 = rl_f(ex0, jp + 3), d1 = rl_f(ex1, jp + 3);
            int r1 = hi ? sB : sA;
            int r2 = hi ? sD : sC;
            float w1 = hi ? (myq ? b1 : b0) : (myq ? a1 : a0);
            float w2 = hi ? (myq ? d1 : d0) : (myq ? c1 : c0);
            float4 h1 = *(const float4*)&Hf[(size_t)r1 * 128 + colbase];
            float4 h2 = *(const float4*)&Hf[(size_t)r2 * 128 + colbase];
            acc.x = fmaf(w1, h1.x, acc.x);
            acc.y = fmaf(w1, h1.y, acc.y);
            acc.z = fmaf(w1, h1.z, acc.z);
            acc.w = fmaf(w1, h1.w, acc.w);
            acc2.x = fmaf(w2, h2.x, acc2.x);
            acc2.y = fmaf(w2, h2.y, acc2.y);
            acc2.z = fmaf(w2, h2.z, acc2.z);
            acc2.w = fmaf(w2, h2.w, acc2.w);
        }
        for (; jp < cntj; jp += 2) {
            int sA = rl_i(s_l, jp);
            float a0 = rl_f(ex0, jp), a1 = rl_f(ex1, jp);
            int sB = sA;
            float b0 = 0.f, b1 = 0.f;
            if (jp + 1 < cntj) {
                sB = rl_i(s_l, jp + 1);
                b0 = rl_f(ex0, jp + 1);
                b1 = rl_f(ex1, jp + 1);
            }
            int r1 = hi ? sB : sA;
            float w1 = hi ? (myq ? b1 : b0) : (myq ? a1 : a0);
            float4 h1 = *(const float4*)&Hf[(size_t)r1 * 128 + colbase];
            acc.x = fmaf(w1, h1.x, acc.x);
            acc.y = fmaf(w1, h1.y, acc.y);
            acc.z = fmaf(w1, h1.z, acc.z);
            acc.w = fmaf(w1, h1.w, acc.w);
        }
    }
    acc.x += acc2.x;
    acc.y += acc2.y;
    acc.z += acc2.z;
    acc.w += acc2.w;
    acc.x += __shfl_xor(acc.x, 32);
    acc.y += __shfl_xor(acc.y, 32);
    acc.z += __shfl_xor(acc.z, 32);
    acc.w += __shfl_xor(acc.w, 32);
    for (int m = 32; m >= 1; m >>= 1) {
        z0 += __shfl_xor(z0, m);
        z1 += __shfl_xor(z1, m);
    }
    if (lane < 32) {
        float zinv = myq ? (1.f / z1) : (1.f / z0);
        float4 b = *(const float4*)&bias[colbase];
        float4 o;
        o.x = fmaxf(fmaf(acc.x, zinv, b.x), 0.f);
        o.y = fmaxf(fmaf(acc.y, zinv, b.y), 0.f);
        o.z = fmaxf(fmaf(acc.z, zinv, b.z), 0.f);
        o.w = fmaxf(fmaf(acc.w, zinv, b.w), 0.f);
        ushort4 hh, ll;
        hh.x = f2bf(o.x); ll.x = f2bf(o.x - bf2f(hh.x));
        hh.y = f2bf(o.y); ll.y = f2bf(o.y - bf2f(hh.y));
        hh.z = f2bf(o.z); ll.z = f2bf(o.z - bf2f(hh.z));
        hh.w = f2bf(o.w); ll.w = f2bf(o.w - bf2f(hh.w));
        // fragment-tile address: k = colbase
        int ch = colbase >> 5;
        int qq = (colbase >> 3) & 3;
        int j = colbase & 7;  // 0 or 4
        size_t tb = ((size_t)(wid >> 4) * 4 + ch) * 512 + ((wid & 15) + 16 * qq) * 8 + j;
        *(ushort4*)&OutH[tb] = hh;
        *(ushort4*)&OutL[tb] = ll;
    }
}

// ---------------- aggregation M=64 (final layer, fp32 out) ----------------

__launch_bounds__(256)
__global__ void k_agg64(const int* __restrict__ ptr, const int* __restrict__ srcv,
                        const float* __restrict__ Hf, const float* __restrict__ als,
                        const float* __restrict__ ald, const float* __restrict__ bias,
                        float* __restrict__ Out, int n) {
    int wid = blockIdx.x * 4 + (threadIdx.x >> 6);
    int lane = threadIdx.x & 63;
    if (wid >= n) return;
    int start = ptr[wid], end = ptr[wid + 1];
    float ad0 = ald[wid];
    int q = lane >> 4;
    int col = (lane & 15) * 4;
    float z = 0.f;
    float4 a1 = make_float4(0.f, 0.f, 0.f, 0.f);
    float4 a2 = make_float4(0.f, 0.f, 0.f, 0.f);
    float4 a3 = make_float4(0.f, 0.f, 0.f, 0.f);
    float4 a4 = make_float4(0.f, 0.f, 0.f, 0.f);

    for (int base = start; base < end; base += 64) {
        int i = base + lane;
        int s_l = 0;
        float ex0 = 0.f;
        if (i < end) {
            s_l = srcv[i];
            float e = als[s_l] + ad0;
            e = e > 0.f ? e : NEG_SLOPE * e;
            ex0 = __expf(e);
        }
        z += ex0;
        int cntj = min(64, end - base);
        int cnt4 = (cntj + 3) & ~3;
        int jp = 0;
        for (; jp + 16 <= cnt4; jp += 16) {
            int r1 = __shfl(s_l, jp + q);
            float w1 = __shfl(ex0, jp + q);
            int r2 = __shfl(s_l, jp + 4 + q);
            float w2 = __shfl(ex0, jp + 4 + q);
            int r3 = __shfl(s_l, jp + 8 + q);
            float w3 = __shfl(ex0, jp + 8 + q);
            int r4 = __shfl(s_l, jp + 12 + q);
            float w4 = __shfl(ex0, jp + 12 + q);
            float4 h1 = *(const float4*)&Hf[(size_t)r1 * 64 + col];
            float4 h2 = *(const float4*)&Hf[(size_t)r2 * 64 + col];
            float4 h3 = *(const float4*)&Hf[(size_t)r3 * 64 + col];
            float4 h4 = *(const float4*)&Hf[(size_t)r4 * 64 + col];
            a1.x = fmaf(w1, h1.x, a1.x);
            a1.y = fmaf(w1, h1.y, a1.y);
            a1.z = fmaf(w1, h1.z, a1.z);
            a1.w = fmaf(w1, h1.w, a1.w);
            a2.x = fmaf(w2, h2.x, a2.x);
            a2.y = fmaf(w2, h2.y, a2.y);
            a2.z = fmaf(w2, h2.z, a2.z);
            a2.w = fmaf(w2, h2.w, a2.w);
            a3.x = fmaf(w3, h3.x, a3.x);
            a3.y = fmaf(w3, h3.y, a3.y);
            a3.z = fmaf(w3, h3.z, a3.z);
            a3.w = fmaf(w3, h3.w, a3.w);
            a4.x = fmaf(w4, h4.x, a4.x);
            a4.y = fmaf(w4, h4.y, a4.y);
            a4.z = fmaf(w4, h4.z, a4.z);
            a4.w = fmaf(w4, h4.w, a4.w);
        }
        for (; jp < cnt4; jp += 4) {
            int r1 = __shfl(s_l, jp + q);
            float w1 = __shfl(ex0, jp + q);
            float4 h1 = *(const float4*)&Hf[(size_t)r1 * 64 + col];
            a1.x = fmaf(w1, h1.x, a1.x);
            a1.y = fmaf(w1, h1.y, a1.y);
            a1.z = fmaf(w1, h1.z, a1.z);
            a1.w = fmaf(w1, h1.w, a1.w);
        }
    }
    a1.x += a2.x + a3.x + a4.x;
    a1.y += a2.y + a3.y + a4.y;
    a1.z += a2.z + a3.z + a4.z;
    a1.w += a2.w + a3.w + a4.w;
    a1.x += __shfl_xor(a1.x, 16);
    a1.y += __shfl_xor(a1.y, 16);
    a1.z += __shfl_xor(a1.z, 16);
    a1.w += __shfl_xor(a1.w, 16);
    a1.x += __shfl_xor(a1.x, 32);
    a1.y += __shfl_xor(a1.y, 32);
    a1.z += __shfl_xor(a1.z, 32);
    a1.w += __shfl_xor(a1.w, 32);
    for (int m = 32; m >= 1; m >>= 1) z += __shfl_xor(z, m);
    if (lane < 16) {
        float zinv = 1.f / z;
        float4 b = *(const float4*)&bias[col];
        float4 o;
        o.x = fmaf(a1.x, zinv, b.x);
        o.y = fmaf(a1.y, zinv, b.y);
        o.z = fmaf(a1.z, zinv, b.z);
        o.w = fmaf(a1.w, zinv, b.w);
        *(float4*)&Out[(size_t)wid * 64 + col] = o;
    }
}

// ---------------- launch ----------------

extern "C" void kernel_launch(void* const* d_in, const int* in_sizes, int n_in,
                              void* d_out, int out_size, void* d_ws, size_t ws_size,
                              hipStream_t stream) {
    const float* x = (const float*)d_in[0];
    const int* ei = (const int*)d_in[1];
    const float* W1 = (const float*)d_in[2];
    const float* as1 = (const float*)d_in[3];
    const float* ad1 = (const float*)d_in[4];
    const float* b1 = (const float*)d_in[5];
    const float* W2 = (const float*)d_in[6];
    const float* as2 = (const float*)d_in[7];
    const float* ad2 = (const float*)d_in[8];
    const float* b2 = (const float*)d_in[9];
    const float* W3 = (const float*)d_in[10];
    const float* as3 = (const float*)d_in[11];
    const float* ad3 = (const float*)d_in[12];
    const float* b3 = (const float*)d_in[13];

    const int N = in_sizes[0] / 128;
    const int E = in_sizes[1] / 2;
    const int NB = (N + BUK_SIZE - 1) / BUK_SIZE;
    const int Npad = (N + 127) & ~127;

    char* p = (char*)d_ws;
    auto alloc = [&](size_t bytes) -> char* {
        char* r = p;
        p += (bytes + 255) & ~(size_t)255;
        return r;
    };
    int* g_cnt = (int*)alloc(256 * 4);
    int* bucket_off = (int*)alloc(257 * 4);
    int* buckets = (int*)alloc((size_t)NB * BUK_CAP * 4);
    int* csr_ptr = (int*)alloc((size_t)(N + 1) * 4);
    int* csr_src = (int*)alloc((size_t)(E + N) * 4);
    float* als = (float*)alloc((size_t)N * 2 * 4);
    float* aldv = (float*)alloc((size_t)N * 2 * 4);
    float* Hbuf = (float*)alloc((size_t)N * 128 * 4);
    u16* XH = (u16*)alloc((size_t)Npad * 128 * 2);
    u16* XL = (u16*)alloc((size_t)Npad * 128 * 2);
    u16* WTh = (u16*)alloc(128 * 128 * 2);
    u16* WTl = (u16*)alloc(128 * 128 * 2);

    const int nbG = Npad / 128;
    const int nbWave = (N * 64 + 255) / 256;
    const int nbAgg64 = (N + 3) / 4;
    const int nbTile = (E + 4095) / 4096;
    const int nbSplit = (Npad * 16 + 255) / 256;

    // ---- binned CSR build (shared by all 3 layers) ----
    k_zero<<<1, 256, 0, stream>>>(g_cnt, 256);
    k_binscatter<<<nbTile, 256, 0, stream>>>(ei, g_cnt, buckets, E, NB);
    k_bucket_scan<<<1, 256, 0, stream>>>(g_cnt, bucket_off, NB, N);
    k_csr<<<NB, 512, 0, stream>>>(g_cnt, bucket_off, buckets, csr_ptr, csr_src, N, NB);

    // ---- layer 1 ----
    k_split<<<nbSplit, 256, 0, stream>>>(x, XH, XL, N, Npad);
    k_wsplit<<<(128 * 128 + 255) / 256, 256, 0, stream>>>(W1, WTh, WTl, 128);
    k_gemm_mfma<128><<<nbG, 256, 0, stream>>>(XH, XL, WTh, WTl, as1, ad1, Hbuf, als, aldv, N);
    k_agg128<<<nbWave, 256, 0, stream>>>(csr_ptr, csr_src, Hbuf, als, aldv, b1, XH, XL, N);

    // ---- layer 2 ----
    k_wsplit<<<(128 * 128 + 255) / 256, 256, 0, stream>>>(W2, WTh, WTl, 128);
    k_gemm_mfma<128><<<nbG, 256, 0, stream>>>(XH, XL, WTh, WTl, as2, ad2, Hbuf, als, aldv, N);
    k_agg128<<<nbWave, 256, 0, stream>>>(csr_ptr, csr_src, Hbuf, als, aldv, b2, XH, XL, N);

    // ---- layer 3 (M=64, mean==identity, no relu) ----
    k_wsplit<<<(128 * 64 + 255) / 256, 256, 0, stream>>>(W3, WTh, WTl, 64);
    k_gemm_mfma<64><<<nbG, 256, 0, stream>>>(XH, XL, WTh, WTl, as3, ad3, Hbuf, als, aldv, N);
    k_agg64<<<nbAgg64, 256, 0, stream>>>(csr_ptr, csr_src, Hbuf, als, aldv, b3,
                                         (float*)d_out, N);
}

// Round 9
// 575.930 us; speedup vs baseline: 1.0913x; 1.0295x over previous
//
#include <hip/hip_runtime.h>
#include <hip/hip_bf16.h>

#define NEG_SLOPE 0.2f
#define BUK_SHIFT 9
#define BUK_SIZE 512
#define BUK_CAP 16384

typedef unsigned short u16;
typedef __attribute__((ext_vector_type(8))) short s8v;
typedef __attribute__((ext_vector_type(4))) float f4v;

__device__ __forceinline__ int rl_i(int v, int l) { return __builtin_amdgcn_readlane(v, l); }
__device__ __forceinline__ float rl_f(float v, int l) {
    union { float f; int i; } u;
    u.f = v;
    u.i = __builtin_amdgcn_readlane(u.i, l);
    return u.f;
}
__device__ __forceinline__ u16 f2bf(float v) {
    unsigned u = __float_as_uint(v);
    unsigned r = u + 0x7FFFu + ((u >> 16) & 1u);
    return (u16)(r >> 16);
}
__device__ __forceinline__ float bf2f(u16 h) { return __uint_as_float(((unsigned)h) << 16); }

// ---------------- binned CSR build ----------------

__global__ void k_zero(int* g_cnt, int nb) {
    int i = blockIdx.x * blockDim.x + threadIdx.x;
    if (i < nb) g_cnt[i] = 0;
}

__launch_bounds__(256)
__global__ void k_binscatter(const int* __restrict__ ei, int* g_cnt, int* buckets,
                             int E, int nb) {
    __shared__ int lcnt[256], lbase[256], lcur[256];
    int t = threadIdx.x;
    if (t < nb) {
        lcnt[t] = 0;
        lcur[t] = 0;
    }
    __syncthreads();
    int tile0 = blockIdx.x * 4096;
    int pk[16], bk[16];
#pragma unroll
    for (int k = 0; k < 16; k++) {
        int idx = tile0 + k * 256 + t;
        bk[k] = -1;
        if (idx < E) {
            int s = ei[idx];
            int d = ei[E + idx];
            bk[k] = d >> BUK_SHIFT;
            pk[k] = (s << BUK_SHIFT) | (d & (BUK_SIZE - 1));
            atomicAdd(&lcnt[bk[k]], 1);
        }
    }
    __syncthreads();
    if (t < nb && lcnt[t] > 0) lbase[t] = atomicAdd(&g_cnt[t], lcnt[t]);
    __syncthreads();
#pragma unroll
    for (int k = 0; k < 16; k++) {
        if (bk[k] >= 0) {
            int p = lbase[bk[k]] + atomicAdd(&lcur[bk[k]], 1);
            if (p < BUK_CAP) buckets[(bk[k] << 14) + p] = pk[k];
        }
    }
}

// One block per bucket. Recomputes bucket offsets internally (512-wide LDS scan over
// <=256 bucket totals), then local per-node count + scan + scatter into the bucket's
// contiguous csr window. Emits csr_ptr and self-loops.
__launch_bounds__(512)
__global__ void k_csr(const int* __restrict__ g_cnt, const int* __restrict__ buckets,
                      int* csr_ptr, int* csr_src, int n, int nb) {
    __shared__ int lcnt[512], lsc[512], lcur[512], bsc[512];
    int b = blockIdx.x;
    int t = threadIdx.x;
    int nodes = min(BUK_SIZE, n - b * BUK_SIZE);
    int cnt = min(g_cnt[b], BUK_CAP);
    const int* bp = &buckets[b << 14];

    // bucket-offset scan (inclusive over all nb buckets)
    int bv = 0;
    if (t < nb) bv = min(g_cnt[t], BUK_CAP) + min(BUK_SIZE, n - t * BUK_SIZE);
    bsc[t] = bv;
    __syncthreads();
    for (int off = 1; off < 512; off <<= 1) {
        int x = (t >= off) ? bsc[t - off] : 0;
        __syncthreads();
        bsc[t] += x;
        __syncthreads();
    }
    int boff = bsc[b] - (cnt + nodes);  // exclusive prefix for this bucket
    int total = bsc[nb - 1];
    __syncthreads();

    lcnt[t] = 0;
    __syncthreads();
    for (int i = t; i < cnt; i += 512) atomicAdd(&lcnt[bp[i] & (BUK_SIZE - 1)], 1);
    __syncthreads();
    int myc = (t < nodes) ? (lcnt[t] + 1) : 0;
    lsc[t] = myc;
    __syncthreads();
    for (int off = 1; off < 512; off <<= 1) {
        int x = (t >= off) ? lsc[t - off] : 0;
        __syncthreads();
        lsc[t] += x;
        __syncthreads();
    }
    int excl = lsc[t] - myc;
    lcur[t] = excl;
    if (t < nodes) csr_ptr[b * BUK_SIZE + t] = boff + excl;
    if (b == nb - 1 && t == 0) csr_ptr[n] = total;
    __syncthreads();
    for (int i = t; i < cnt; i += 512) {
        int v = bp[i];
        int ld = v & (BUK_SIZE - 1);
        int p = atomicAdd(&lcur[ld], 1);
        csr_src[boff + p] = v >> BUK_SHIFT;
    }
    if (t < nodes) {
        int p = atomicAdd(&lcur[t], 1);
        csr_src[boff + p] = b * BUK_SIZE + t;
    }
}

// ---------------- W split: all three layers in one dispatch ----------------
// W[128,M] -> fragment tiles (16 cols x 32 k = 1KB, frag order lane*8+j).

__global__ void k_wsplit_all(const float* __restrict__ W1, const float* __restrict__ W2,
                             const float* __restrict__ W3, u16* __restrict__ T1h,
                             u16* __restrict__ T1l, u16* __restrict__ T2h,
                             u16* __restrict__ T2l, u16* __restrict__ T3h,
                             u16* __restrict__ T3l) {
    int t = blockIdx.x * 256 + threadIdx.x;
    const float* W;
    u16 *Th, *Tl;
    int M, idx;
    if (t < 16384) {
        W = W1; Th = T1h; Tl = T1l; M = 128; idx = t;
    } else if (t < 32768) {
        W = W2; Th = T2h; Tl = T2l; M = 128; idx = t - 16384;
    } else if (t < 40960) {
        W = W3; Th = T3h; Tl = T3l; M = 64; idx = t - 32768;
    } else {
        return;
    }
    int c = idx >> 7, k = idx & 127;
    float v = W[(size_t)k * M + c];
    u16 h = f2bf(v);
    u16 l = f2bf(v - bf2f(h));
    int ct = c >> 4, ch = k >> 5, q = (k >> 3) & 3, j = k & 7;
    size_t addr = ((size_t)ct * 4 + ch) * 512 + ((c & 15) + 16 * q) * 8 + j;
    Th[addr] = h;
    Tl[addr] = l;
}

// ---------------- MFMA GEMM (bf16x3 split) + fused attention logits ----------------
// 256 thr = 4 waves; block 128 rows x M cols; wave 32 rows (2 row-tiles) x M cols.
// FP32X: A loaded from row-major fp32 X, split in-register (layer 1).
// else: A loaded from fragment-tile bf16 hi/lo (layers 2,3).

__device__ __forceinline__ void load_split_f32(const float* __restrict__ X, int row,
                                               int koff, int N, s8v& hi, s8v& lo) {
    float v[8];
    if (row < N) {
        float4 a = *(const float4*)&X[(size_t)row * 128 + koff];
        float4 b = *(const float4*)&X[(size_t)row * 128 + koff + 4];
        v[0] = a.x; v[1] = a.y; v[2] = a.z; v[3] = a.w;
        v[4] = b.x; v[5] = b.y; v[6] = b.z; v[7] = b.w;
    } else {
#pragma unroll
        for (int i = 0; i < 8; i++) v[i] = 0.f;
    }
    union { s8v s; u16 u[8]; } H, L;
#pragma unroll
    for (int i = 0; i < 8; i++) {
        H.u[i] = f2bf(v[i]);
        L.u[i] = f2bf(v[i] - bf2f(H.u[i]));
    }
    hi = H.s;
    lo = L.s;
}

template <int M, bool FP32X>
__launch_bounds__(256)
__global__ void k_gemm_mfma(const float* __restrict__ Xf, const u16* __restrict__ XH,
                            const u16* __restrict__ XL, const u16* __restrict__ WTh,
                            const u16* __restrict__ WTl, const float* __restrict__ asrc,
                            const float* __restrict__ adst, float* __restrict__ Hout,
                            float* __restrict__ als, float* __restrict__ ald, int nrows) {
    const int CT = M / 16;
    const int H = (M == 128) ? 2 : 1;
    int tid = threadIdx.x;
    int wv = tid >> 6, lane = tid & 63;
    int q = lane >> 4, nl = lane & 15;
    int R0 = blockIdx.x * 128 + wv * 32;
    int rt0 = R0 >> 4;

    f4v acc[2][CT];
    f4v z4 = {0.f, 0.f, 0.f, 0.f};
#pragma unroll
    for (int rt = 0; rt < 2; rt++)
#pragma unroll
        for (int ct = 0; ct < CT; ct++) acc[rt][ct] = z4;

#pragma unroll
    for (int ch = 0; ch < 4; ch++) {
        s8v ah0, al0, ah1, al1;
        if (FP32X) {
            int koff = ch * 32 + q * 8;
            load_split_f32(Xf, R0 + nl, koff, nrows, ah0, al0);
            load_split_f32(Xf, R0 + 16 + nl, koff, nrows, ah1, al1);
        } else {
            size_t a0 = ((size_t)rt0 * 4 + ch) * 512 + lane * 8;
            size_t a1 = ((size_t)(rt0 + 1) * 4 + ch) * 512 + lane * 8;
            ah0 = *(const s8v*)&XH[a0];
            al0 = *(const s8v*)&XL[a0];
            ah1 = *(const s8v*)&XH[a1];
            al1 = *(const s8v*)&XL[a1];
        }
#pragma unroll
        for (int ct = 0; ct < CT; ct++) {
            size_t bb = ((size_t)ct * 4 + ch) * 512 + lane * 8;
            s8v bh = *(const s8v*)&WTh[bb];
            s8v bl = *(const s8v*)&WTl[bb];
            acc[0][ct] = __builtin_amdgcn_mfma_f32_16x16x32_bf16(ah0, bh, acc[0][ct], 0, 0, 0);
            acc[0][ct] = __builtin_amdgcn_mfma_f32_16x16x32_bf16(ah0, bl, acc[0][ct], 0, 0, 0);
            acc[0][ct] = __builtin_amdgcn_mfma_f32_16x16x32_bf16(al0, bh, acc[0][ct], 0, 0, 0);
            acc[1][ct] = __builtin_amdgcn_mfma_f32_16x16x32_bf16(ah1, bh, acc[1][ct], 0, 0, 0);
            acc[1][ct] = __builtin_amdgcn_mfma_f32_16x16x32_bf16(ah1, bl, acc[1][ct], 0, 0, 0);
            acc[1][ct] = __builtin_amdgcn_mfma_f32_16x16x32_bf16(al1, bh, acc[1][ct], 0, 0, 0);
        }
    }

    float av[CT], dvv[CT];
#pragma unroll
    for (int ct = 0; ct < CT; ct++) {
        av[ct] = asrc[ct * 16 + nl];
        dvv[ct] = adst[ct * 16 + nl];
    }
    float ps[2][4][2], pd[2][4][2];
#pragma unroll
    for (int rt = 0; rt < 2; rt++)
#pragma unroll
        for (int r = 0; r < 4; r++)
            for (int h = 0; h < 2; h++) ps[rt][r][h] = pd[rt][r][h] = 0.f;
#pragma unroll
    for (int rt = 0; rt < 2; rt++)
#pragma unroll
        for (int ct = 0; ct < CT; ct++) {
            int h = (M == 128) ? (ct >> 2) : 0;
#pragma unroll
            for (int r = 0; r < 4; r++) {
                ps[rt][r][h] = fmaf(acc[rt][ct][r], av[ct], ps[rt][r][h]);
                pd[rt][r][h] = fmaf(acc[rt][ct][r], dvv[ct], pd[rt][r][h]);
            }
        }

#pragma unroll
    for (int rt = 0; rt < 2; rt++)
#pragma unroll
        for (int ct = 0; ct < CT; ct++)
#pragma unroll
            for (int r = 0; r < 4; r++) {
                int row = R0 + rt * 16 + q * 4 + r;
                if (row < nrows) Hout[(size_t)row * M + ct * 16 + nl] = acc[rt][ct][r];
            }

#pragma unroll
    for (int rt = 0; rt < 2; rt++)
#pragma unroll
        for (int r = 0; r < 4; r++)
#pragma unroll
            for (int h = 0; h < H; h++) {
                float v1 = ps[rt][r][h], v2 = pd[rt][r][h];
                for (int m = 1; m <= 8; m <<= 1) {
                    v1 += __shfl_xor(v1, m);
                    v2 += __shfl_xor(v2, m);
                }
                int row = R0 + rt * 16 + q * 4 + r;
                if (nl == 0 && row < nrows) {
                    als[(size_t)row * H + h] = v1;
                    ald[(size_t)row * H + h] = v2;
                }
            }
}

// ---------------- aggregation M=128 (readlane, 2 loads in flight) ----------------
// Writes bf16 hi/lo in fragment-tile layout (next layer's GEMM input), with ReLU.

__global__ void k_agg128(const int* __restrict__ ptr, const int* __restrict__ srcv,
                         const float* __restrict__ Hf, const float* __restrict__ als,
                         const float* __restrict__ ald, const float* __restrict__ bias,
                         u16* __restrict__ OutH, u16* __restrict__ OutL, int n) {
    int wid = (blockIdx.x * blockDim.x + threadIdx.x) >> 6;
    int lane = threadIdx.x & 63;
    if (wid >= n) return;
    int start = ptr[wid], end = ptr[wid + 1];
    float2 adv = *(const float2*)&ald[(size_t)wid * 2];
    int hi = lane >> 5;
    int myq = (lane >> 4) & 1;
    int colbase = (lane & 31) * 4;
    float z0 = 0.f, z1 = 0.f;
    float4 acc = make_float4(0.f, 0.f, 0.f, 0.f);
    float4 acc2 = make_float4(0.f, 0.f, 0.f, 0.f);

    for (int base = start; base < end; base += 64) {
        int i = base + lane;
        int s_l = 0;
        float ex0 = 0.f, ex1 = 0.f;
        if (i < end) {
            s_l = srcv[i];
            float2 av = *(const float2*)&als[(size_t)s_l * 2];
            float e0 = av.x + adv.x;
            e0 = e0 > 0.f ? e0 : NEG_SLOPE * e0;
            ex0 = __expf(e0);
            float e1 = av.y + adv.y;
            e1 = e1 > 0.f ? e1 : NEG_SLOPE * e1;
            ex1 = __expf(e1);
        }
        z0 += ex0;
        z1 += ex1;
        int cntj = min(64, end - base);
        int jp = 0;
        for (; jp + 4 <= cntj; jp += 4) {
            int sA = rl_i(s_l, jp), sB = rl_i(s_l, jp + 1);
            int sC = rl_i(s_l, jp + 2), sD = rl_i(s_l, jp + 3);
            float a0 = rl_f(ex0, jp), a1 = rl_f(ex1, jp);
            float b0 = rl_f(ex0, jp + 1), b1 = rl_f(ex1, jp + 1);
            float c0 = rl_f(ex0, jp + 2), c1 = rl_f(ex1, jp + 2);
            float d0 = rl_f(ex0, jp + 3), d1 = rl_f(ex1, jp + 3);
            int r1 = hi ? sB : sA;
            int r2 = hi ? sD : sC;
            float w1 = hi ? (myq ? b1 : b0) : (myq ? a1 : a0);
            float w2 = hi ? (myq ? d1 : d0) : (myq ? c1 : c0);
            float4 h1 = *(const float4*)&Hf[(size_t)r1 * 128 + colbase];
            float4 h2 = *(const float4*)&Hf[(size_t)r2 * 128 + colbase];
            acc.x = fmaf(w1, h1.x, acc.x);
            acc.y = fmaf(w1, h1.y, acc.y);
            acc.z = fmaf(w1, h1.z, acc.z);
            acc.w = fmaf(w1, h1.w, acc.w);
            acc2.x = fmaf(w2, h2.x, acc2.x);
            acc2.y = fmaf(w2, h2.y, acc2.y);
            acc2.z = fmaf(w2, h2.z, acc2.z);
            acc2.w = fmaf(w2, h2.w, acc2.w);
        }
        for (; jp < cntj; jp += 2) {
            int sA = rl_i(s_l, jp);
            float a0 = rl_f(ex0, jp), a1 = rl_f(ex1, jp);
            int sB = sA;
            float b0 = 0.f, b1 = 0.f;
            if (jp + 1 < cntj) {
                sB = rl_i(s_l, jp + 1);
                b0 = rl_f(ex0, jp + 1);
                b1 = rl_f(ex1, jp + 1);
            }
            int r1 = hi ? sB : sA;
            float w1 = hi ? (myq ? b1 : b0) : (myq ? a1 : a0);
            float4 h1 = *(const float4*)&Hf[(size_t)r1 * 128 + colbase];
            acc.x = fmaf(w1, h1.x, acc.x);
            acc.y = fmaf(w1, h1.y, acc.y);
            acc.z = fmaf(w1, h1.z, acc.z);
            acc.w = fmaf(w1, h1.w, acc.w);
        }
    }
    acc.x += acc2.x;
    acc.y += acc2.y;
    acc.z += acc2.z;
    acc.w += acc2.w;
    acc.x += __shfl_xor(acc.x, 32);
    acc.y += __shfl_xor(acc.y, 32);
    acc.z += __shfl_xor(acc.z, 32);
    acc.w += __shfl_xor(acc.w, 32);
    for (int m = 32; m >= 1; m >>= 1) {
        z0 += __shfl_xor(z0, m);
        z1 += __shfl_xor(z1, m);
    }
    if (lane < 32) {
        float zinv = myq ? (1.f / z1) : (1.f / z0);
        float4 b = *(const float4*)&bias[colbase];
        float4 o;
        o.x = fmaxf(fmaf(acc.x, zinv, b.x), 0.f);
        o.y = fmaxf(fmaf(acc.y, zinv, b.y), 0.f);
        o.z = fmaxf(fmaf(acc.z, zinv, b.z), 0.f);
        o.w = fmaxf(fmaf(acc.w, zinv, b.w), 0.f);
        ushort4 hh, ll;
        hh.x = f2bf(o.x); ll.x = f2bf(o.x - bf2f(hh.x));
        hh.y = f2bf(o.y); ll.y = f2bf(o.y - bf2f(hh.y));
        hh.z = f2bf(o.z); ll.z = f2bf(o.z - bf2f(hh.z));
        hh.w = f2bf(o.w); ll.w = f2bf(o.w - bf2f(hh.w));
        int ch = colbase >> 5;
        int qq = (colbase >> 3) & 3;
        int j = colbase & 7;
        size_t tb = ((size_t)(wid >> 4) * 4 + ch) * 512 + ((wid & 15) + 16 * qq) * 8 + j;
        *(ushort4*)&OutH[tb] = hh;
        *(ushort4*)&OutL[tb] = ll;
    }
}

// ---------------- aggregation M=64 (final layer, fp32 out) ----------------

__launch_bounds__(256)
__global__ void k_agg64(const int* __restrict__ ptr, const int* __restrict__ srcv,
                        const float* __restrict__ Hf, const float* __restrict__ als,
                        const float* __restrict__ ald, const float* __restrict__ bias,
                        float* __restrict__ Out, int n) {
    int wid = blockIdx.x * 4 + (threadIdx.x >> 6);
    int lane = threadIdx.x & 63;
    if (wid >= n) return;
    int start = ptr[wid], end = ptr[wid + 1];
    float ad0 = ald[wid];
    int q = lane >> 4;
    int col = (lane & 15) * 4;
    float z = 0.f;
    float4 a1 = make_float4(0.f, 0.f, 0.f, 0.f);
    float4 a2 = make_float4(0.f, 0.f, 0.f, 0.f);
    float4 a3 = make_float4(0.f, 0.f, 0.f, 0.f);
    float4 a4 = make_float4(0.f, 0.f, 0.f, 0.f);

    for (int base = start; base < end; base += 64) {
        int i = base + lane;
        int s_l = 0;
        float ex0 = 0.f;
        if (i < end) {
            s_l = srcv[i];
            float e = als[s_l] + ad0;
            e = e > 0.f ? e : NEG_SLOPE * e;
            ex0 = __expf(e);
        }
        z += ex0;
        int cntj = min(64, end - base);
        int cnt4 = (cntj + 3) & ~3;
        int jp = 0;
        for (; jp + 16 <= cnt4; jp += 16) {
            int r1 = __shfl(s_l, jp + q);
            float w1 = __shfl(ex0, jp + q);
            int r2 = __shfl(s_l, jp + 4 + q);
            float w2 = __shfl(ex0, jp + 4 + q);
            int r3 = __shfl(s_l, jp + 8 + q);
            float w3 = __shfl(ex0, jp + 8 + q);
            int r4 = __shfl(s_l, jp + 12 + q);
            float w4 = __shfl(ex0, jp + 12 + q);
            float4 h1 = *(const float4*)&Hf[(size_t)r1 * 64 + col];
            float4 h2 = *(const float4*)&Hf[(size_t)r2 * 64 + col];
            float4 h3 = *(const float4*)&Hf[(size_t)r3 * 64 + col];
            float4 h4 = *(const float4*)&Hf[(size_t)r4 * 64 + col];
            a1.x = fmaf(w1, h1.x, a1.x);
            a1.y = fmaf(w1, h1.y, a1.y);
            a1.z = fmaf(w1, h1.z, a1.z);
            a1.w = fmaf(w1, h1.w, a1.w);
            a2.x = fmaf(w2, h2.x, a2.x);
            a2.y = fmaf(w2, h2.y, a2.y);
            a2.z = fmaf(w2, h2.z, a2.z);
            a2.w = fmaf(w2, h2.w, a2.w);
            a3.x = fmaf(w3, h3.x, a3.x);
            a3.y = fmaf(w3, h3.y, a3.y);
            a3.z = fmaf(w3, h3.z, a3.z);
            a3.w = fmaf(w3, h3.w, a3.w);
            a4.x = fmaf(w4, h4.x, a4.x);
            a4.y = fmaf(w4, h4.y, a4.y);
            a4.z = fmaf(w4, h4.z, a4.z);
            a4.w = fmaf(w4, h4.w, a4.w);
        }
        for (; jp < cnt4; jp += 4) {
            int r1 = __shfl(s_l, jp + q);
            float w1 = __shfl(ex0, jp + q);
            float4 h1 = *(const float4*)&Hf[(size_t)r1 * 64 + col];
            a1.x = fmaf(w1, h1.x, a1.x);
            a1.y = fmaf(w1, h1.y, a1.y);
            a1.z = fmaf(w1, h1.z, a1.z);
            a1.w = fmaf(w1, h1.w, a1.w);
        }
    }
    a1.x += a2.x + a3.x + a4.x;
    a1.y += a2.y + a3.y + a4.y;
    a1.z += a2.z + a3.z + a4.z;
    a1.w += a2.w + a3.w + a4.w;
    a1.x += __shfl_xor(a1.x, 16);
    a1.y += __shfl_xor(a1.y, 16);
    a1.z += __shfl_xor(a1.z, 16);
    a1.w += __shfl_xor(a1.w, 16);
    a1.x += __shfl_xor(a1.x, 32);
    a1.y += __shfl_xor(a1.y, 32);
    a1.z += __shfl_xor(a1.z, 32);
    a1.w += __shfl_xor(a1.w, 32);
    for (int m = 32; m >= 1; m >>= 1) z += __shfl_xor(z, m);
    if (lane < 16) {
        float zinv = 1.f / z;
        float4 b = *(const float4*)&bias[col];
        float4 o;
        o.x = fmaf(a1.x, zinv, b.x);
        o.y = fmaf(a1.y, zinv, b.y);
        o.z = fmaf(a1.z, zinv, b.z);
        o.w = fmaf(a1.w, zinv, b.w);
        *(float4*)&Out[(size_t)wid * 64 + col] = o;
    }
}

// ---------------- launch ----------------

extern "C" void kernel_launch(void* const* d_in, const int* in_sizes, int n_in,
                              void* d_out, int out_size, void* d_ws, size_t ws_size,
                              hipStream_t stream) {
    const float* x = (const float*)d_in[0];
    const int* ei = (const int*)d_in[1];
    const float* W1 = (const float*)d_in[2];
    const float* as1 = (const float*)d_in[3];
    const float* ad1 = (const float*)d_in[4];
    const float* b1 = (const float*)d_in[5];
    const float* W2 = (const float*)d_in[6];
    const float* as2 = (const float*)d_in[7];
    const float* ad2 = (const float*)d_in[8];
    const float* b2 = (const float*)d_in[9];
    const float* W3 = (const float*)d_in[10];
    const float* as3 = (const float*)d_in[11];
    const float* ad3 = (const float*)d_in[12];
    const float* b3 = (const float*)d_in[13];

    const int N = in_sizes[0] / 128;
    const int E = in_sizes[1] / 2;
    const int NB = (N + BUK_SIZE - 1) / BUK_SIZE;
    const int Npad = (N + 127) & ~127;

    char* p = (char*)d_ws;
    auto alloc = [&](size_t bytes) -> char* {
        char* r = p;
        p += (bytes + 255) & ~(size_t)255;
        return r;
    };
    int* g_cnt = (int*)alloc(256 * 4);
    int* buckets = (int*)alloc((size_t)NB * BUK_CAP * 4);
    int* csr_ptr = (int*)alloc((size_t)(N + 1) * 4);
    int* csr_src = (int*)alloc((size_t)(E + N) * 4);
    float* als = (float*)alloc((size_t)N * 2 * 4);
    float* aldv = (float*)alloc((size_t)N * 2 * 4);
    float* Hbuf = (float*)alloc((size_t)N * 128 * 4);
    u16* XH = (u16*)alloc((size_t)Npad * 128 * 2);
    u16* XL = (u16*)alloc((size_t)Npad * 128 * 2);
    u16* WT1h = (u16*)alloc(128 * 128 * 2);
    u16* WT1l = (u16*)alloc(128 * 128 * 2);
    u16* WT2h = (u16*)alloc(128 * 128 * 2);
    u16* WT2l = (u16*)alloc(128 * 128 * 2);
    u16* WT3h = (u16*)alloc(128 * 64 * 2);
    u16* WT3l = (u16*)alloc(128 * 64 * 2);

    const int nbG = Npad / 128;
    const int nbWave = (N * 64 + 255) / 256;
    const int nbAgg64 = (N + 3) / 4;
    const int nbTile = (E + 4095) / 4096;

    // ---- binned CSR build (shared by all 3 layers) ----
    k_zero<<<1, 256, 0, stream>>>(g_cnt, 256);
    k_binscatter<<<nbTile, 256, 0, stream>>>(ei, g_cnt, buckets, E, NB);
    k_csr<<<NB, 512, 0, stream>>>(g_cnt, buckets, csr_ptr, csr_src, N, NB);

    // ---- all W splits in one dispatch ----
    k_wsplit_all<<<160, 256, 0, stream>>>(W1, W2, W3, WT1h, WT1l, WT2h, WT2l, WT3h, WT3l);

    // ---- layer 1 (reads fp32 x directly, splits in-register) ----
    k_gemm_mfma<128, true><<<nbG, 256, 0, stream>>>(x, nullptr, nullptr, WT1h, WT1l,
                                                    as1, ad1, Hbuf, als, aldv, N);
    k_agg128<<<nbWave, 256, 0, stream>>>(csr_ptr, csr_src, Hbuf, als, aldv, b1, XH, XL, N);

    // ---- layer 2 ----
    k_gemm_mfma<128, false><<<nbG, 256, 0, stream>>>(nullptr, XH, XL, WT2h, WT2l,
                                                     as2, ad2, Hbuf, als, aldv, N);
    k_agg128<<<nbWave, 256, 0, stream>>>(csr_ptr, csr_src, Hbuf, als, aldv, b2, XH, XL, N);

    // ---- layer 3 (M=64, mean==identity, no relu) ----
    k_gemm_mfma<64, false><<<nbG, 256, 0, stream>>>(nullptr, XH, XL, WT3h, WT3l,
                                                    as3, ad3, Hbuf, als, aldv, N);
    k_agg64<<<nbAgg64, 256, 0, stream>>>(csr_ptr, csr_src, Hbuf, als, aldv, b3,
                                         (float*)d_out, N);
}